// Round 3
// baseline (725.139 us; speedup 1.0000x reference)
//
#include <hip/hip_runtime.h>
#include <stdint.h>
#include <stddef.h>

#define DIM   2048
#define NEXP  64
#define NTOK  32768
#define OFF_IDX  (NTOK*NEXP)          // 2097152
#define OFF_TSC  (OFF_IDX + NTOK*2)   // 2162688

typedef __attribute__((ext_vector_type(4))) float f32x4;

// ---------------------------------------------------------------------------
// Transpose W[e][d] -> Wt[d][e]  (512 KB in d_ws). Makes the per-d expert row
// contiguous so the main kernel's W reads are wave-uniform scalar loads.
// ---------------------------------------------------------------------------
__global__ __launch_bounds__(256) void wtrans(const float* __restrict__ W,
                                              float* __restrict__ Wt) {
    int idx = blockIdx.x * 256 + threadIdx.x;   // 0..131071
    int e = idx & 63, d = idx >> 6;
    Wt[idx] = W[e * DIM + d];
}

// ---------------------------------------------------------------------------
// Emulates np/BLAS fp32 semantics: logit[t][e] = sequential fmaf chain over
// d = 0..2047 (ascending), then + b[e] as a separate fp32 add.
// Block = 256 thr = 4 waves, owns 64 tokens. Wave eg handles experts
// [eg*16, eg*16+16) for all 64 tokens (lane = token). W reads wave-uniform.
// Phase 2 (wave 0): per-token softmax + top-2 (lowest-index ties) from LDS.
// ---------------------------------------------------------------------------
__global__ __launch_bounds__(256, 2) void router_seq(
        const float* __restrict__ X, const float* __restrict__ Wt,
        const float* __restrict__ B, float* __restrict__ out) {
    __shared__ float ls[64][65];               // logits [token][expert], pad
    const int lane = threadIdx.x & 63;
    const int eg   = threadIdx.x >> 6;         // wave-uniform expert group
    const int e0   = eg * 16;
    const int t    = blockIdx.x * 64 + lane;
    const float* xrow = X + (size_t)t * DIM;

    float acc[16];
#pragma unroll
    for (int e = 0; e < 16; e++) acc[e] = 0.0f;

    // double-buffered x chunk (64 floats) in registers
    f32x4 cur[16], nxt[16];
#pragma unroll
    for (int q = 0; q < 16; q++) cur[q] = *(const f32x4*)(xrow + q * 4);

#pragma unroll 1
    for (int kb = 0; kb < DIM; kb += 64) {
        const int kn = (kb + 64 < DIM) ? kb + 64 : kb;
#pragma unroll
        for (int q = 0; q < 16; q++) nxt[q] = *(const f32x4*)(xrow + kn + q * 4);

#pragma unroll
        for (int q = 0; q < 16; q++) {
#pragma unroll
            for (int j = 0; j < 4; j++) {
                const float xv = cur[q][j];
                const float* wr = Wt + (size_t)(kb + q * 4 + j) * NEXP + e0;
#pragma unroll
                for (int e = 0; e < 16; e++)
                    acc[e] = fmaf(xv, wr[e], acc[e]);   // strict in-order chain
            }
        }
#pragma unroll
        for (int q = 0; q < 16; q++) cur[q] = nxt[q];
    }

    // bias (separate fp32 add, like einsum-result + b) -> LDS
#pragma unroll
    for (int e = 0; e < 16; e++) ls[lane][e0 + e] = acc[e] + B[e0 + e];

    __syncthreads();

    // -------- phase 2: wave 0, lane = token --------
    if (eg == 0) {
        const int t2 = blockIdx.x * 64 + lane;
        float l[64];
#pragma unroll
        for (int e = 0; e < 64; e++) l[e] = ls[lane][e];

        // max
        float m = l[0];
#pragma unroll
        for (int e = 1; e < 64; e++) m = fmaxf(m, l[e]);

        // top-2 on logits, ascending scan, strict > => lowest-index ties
        float v1 = -3.4e38f, v2 = -3.4e38f;
        int   i1 = 0,        i2 = 0;
#pragma unroll
        for (int e = 0; e < 64; e++) {
            float v = l[e];
            if (v > v1)      { v2 = v1; i2 = i1; v1 = v; i1 = e; }
            else if (v > v2) { v2 = v;  i2 = e; }
        }

        // softmax
        float den = 0.0f;
#pragma unroll
        for (int e = 0; e < 64; e++) { l[e] = __expf(l[e] - m); den += l[e]; }
        const float inv = 1.0f / den;

#pragma unroll
        for (int q = 0; q < 16; q++) {
            f32x4 v;
#pragma unroll
            for (int j = 0; j < 4; j++) v[j] = l[q * 4 + j] * inv;
            *(f32x4*)(out + (size_t)t2 * 64 + q * 4) = v;
        }
        out[OFF_IDX + (size_t)t2 * 2 + 0] = (float)i1;
        out[OFF_IDX + (size_t)t2 * 2 + 1] = (float)i2;
        out[OFF_TSC + (size_t)t2 * 2 + 0] = __expf(v1 - m) * inv;
        out[OFF_TSC + (size_t)t2 * 2 + 1] = __expf(v2 - m) * inv;
    }
}

extern "C" void kernel_launch(void* const* d_in, const int* in_sizes, int n_in,
                              void* d_out, int out_size, void* d_ws, size_t ws_size,
                              hipStream_t stream) {
    const float* X = (const float*)d_in[0];   // [4,8192,2048] f32
    const float* W = (const float*)d_in[1];   // [64,2048] f32
    const float* b = (const float*)d_in[2];   // [64] f32
    float* out = (float*)d_out;
    float* Wt  = (float*)d_ws;                // 512 KB needed

    wtrans<<<512, 256, 0, stream>>>(W, Wt);
    router_seq<<<NTOK / 64, 256, 0, stream>>>(X, Wt, b, out);
}

// Round 4
// 278.769 us; speedup vs baseline: 2.6012x; 2.6012x over previous
//
#include <hip/hip_runtime.h>
#include <stdint.h>
#include <stddef.h>

#define DIM   2048
#define NEXP  64
#define NTOK  32768
#define OFF_IDX  (NTOK*NEXP)          // 2097152
#define OFF_TSC  (OFF_IDX + NTOK*2)   // 2162688

typedef __attribute__((ext_vector_type(4))) float f32x4;

// ---------------------------------------------------------------------------
// Transpose W[e][d] -> Wt[d][e]  (512 KB in d_ws). Per-d expert row is
// contiguous -> wave-uniform scalar (s_load) reads in the main kernel.
// ---------------------------------------------------------------------------
__global__ __launch_bounds__(256) void wtrans(const float* __restrict__ W,
                                              float* __restrict__ Wt) {
    int idx = blockIdx.x * 256 + threadIdx.x;   // 0..131071
    int e = idx & 63, d = idx >> 6;
    Wt[idx] = W[e * DIM + d];
}

// ---------------------------------------------------------------------------
// np/BLAS fp32 semantics preserved EXACTLY (passed R3): logit[t][e] is one
// sequential fmaf chain over d = 0..2047 ascending, then + b[e].
// Schedule change only: 512 thr = 8 waves/block, wave eg owns experts
// [8eg, 8eg+8) for the block's 64 tokens (lane = token). W reads are
// provably wave-uniform (readfirstlane) -> scalar pipe. 2 blocks/CU.
// ---------------------------------------------------------------------------
__global__ __launch_bounds__(512, 4) void router_seq8(
        const float* __restrict__ X, const float* __restrict__ Wt,
        const float* __restrict__ B, float* __restrict__ out) {
    __shared__ float ls[64][65];               // logits [token][expert], pad
    const int lane = threadIdx.x & 63;
    const int eg   = __builtin_amdgcn_readfirstlane(threadIdx.x >> 6); // 0..7
    const int e0   = eg * 8;
    const int tokb = blockIdx.x * 64;
    const float* xrow = X + (size_t)(tokb + lane) * DIM;
    const float* wrow = Wt + e0;               // + d*64 : uniform address

    float acc[8];
#pragma unroll
    for (int e = 0; e < 8; e++) acc[e] = 0.0f;

    f32x4 cur[8], nxt[8];
#pragma unroll
    for (int q = 0; q < 8; q++) cur[q] = *(const f32x4*)(xrow + q * 4);

#pragma unroll 1
    for (int kb = 0; kb < DIM; kb += 32) {
        const int kn = (kb + 32 < DIM) ? kb + 32 : kb;
#pragma unroll
        for (int q = 0; q < 8; q++) nxt[q] = *(const f32x4*)(xrow + kn + q * 4);

#pragma unroll
        for (int q = 0; q < 8; q++) {
#pragma unroll
            for (int j = 0; j < 4; j++) {
                const float xv = cur[q][j];
                const float* wr = wrow + (size_t)(kb + q * 4 + j) * NEXP;
#pragma unroll
                for (int e = 0; e < 8; e++)
                    acc[e] = fmaf(xv, wr[e], acc[e]);   // strict in-order chain
            }
        }
#pragma unroll
        for (int q = 0; q < 8; q++) cur[q] = nxt[q];
    }

    // bias (separate fp32 add, matching einsum + b) -> LDS
#pragma unroll
    for (int e = 0; e < 8; e++) ls[lane][e0 + e] = acc[e] + B[e0 + e];

    __syncthreads();

    // -------- phase 2: wave 0, lane = token (identical to passing R3) ------
    if (threadIdx.x < 64) {
        const int t2 = tokb + lane;
        float l[64];
#pragma unroll
        for (int e = 0; e < 64; e++) l[e] = ls[lane][e];

        float m = l[0];
#pragma unroll
        for (int e = 1; e < 64; e++) m = fmaxf(m, l[e]);

        // top-2 on logits, ascending scan, strict > => lowest-index ties
        float v1 = -3.4e38f, v2 = -3.4e38f;
        int   i1 = 0,        i2 = 0;
#pragma unroll
        for (int e = 0; e < 64; e++) {
            float v = l[e];
            if (v > v1)      { v2 = v1; i2 = i1; v1 = v; i1 = e; }
            else if (v > v2) { v2 = v;  i2 = e; }
        }

        float den = 0.0f;
#pragma unroll
        for (int e = 0; e < 64; e++) { l[e] = __expf(l[e] - m); den += l[e]; }
        const float inv = 1.0f / den;

#pragma unroll
        for (int q = 0; q < 16; q++) {
            f32x4 v;
#pragma unroll
            for (int j = 0; j < 4; j++) v[j] = l[q * 4 + j] * inv;
            *(f32x4*)(out + (size_t)t2 * 64 + q * 4) = v;
        }
        out[OFF_IDX + (size_t)t2 * 2 + 0] = (float)i1;
        out[OFF_IDX + (size_t)t2 * 2 + 1] = (float)i2;
        out[OFF_TSC + (size_t)t2 * 2 + 0] = __expf(v1 - m) * inv;
        out[OFF_TSC + (size_t)t2 * 2 + 1] = __expf(v2 - m) * inv;
    }
}

extern "C" void kernel_launch(void* const* d_in, const int* in_sizes, int n_in,
                              void* d_out, int out_size, void* d_ws, size_t ws_size,
                              hipStream_t stream) {
    const float* X = (const float*)d_in[0];   // [4,8192,2048] f32
    const float* W = (const float*)d_in[1];   // [64,2048] f32
    const float* b = (const float*)d_in[2];   // [64] f32
    float* out = (float*)d_out;
    float* Wt  = (float*)d_ws;                // 512 KB needed

    wtrans<<<512, 256, 0, stream>>>(W, Wt);
    router_seq8<<<NTOK / 64, 512, 0, stream>>>(X, Wt, b, out);
}

// Round 5
// 157.991 us; speedup vs baseline: 4.5898x; 1.7645x over previous
//
#include <hip/hip_runtime.h>
#include <stdint.h>
#include <stddef.h>

#define DIM   2048
#define NEXP  64
#define NTOK  32768
#define OFF_IDX  (NTOK*NEXP)          // 2097152
#define OFF_TSC  (OFF_IDX + NTOK*2)   // 2162688

typedef __attribute__((ext_vector_type(4))) float f32x4;

// ---------------------------------------------------------------------------
// Transpose W[e][d] -> Wt[d][e]  (512 KB in d_ws). Per-d expert row is
// contiguous -> wave-uniform scalar (s_load) reads in the main kernel.
// ---------------------------------------------------------------------------
__global__ __launch_bounds__(256) void wtrans(const float* __restrict__ W,
                                              float* __restrict__ Wt) {
    int idx = blockIdx.x * 256 + threadIdx.x;   // 0..131071
    int e = idx & 63, d = idx >> 6;
    Wt[idx] = W[e * DIM + d];
}

// ---------------------------------------------------------------------------
// np/BLAS fp32 semantics preserved EXACTLY (passed R3/R4): logit[t][e] is one
// sequential fmaf chain over d = 0..2047 ascending, then + b[e].
// NEW SCHEDULE: X staged via LDS.
//   block = 64 tokens, 512 thr = 8 waves; wave w owns experts [8w, 8w+8).
//   Tile [64 tok][64 d] f32, XOR-swizzled rows (byte ^= 16*(row&7)) so both
//   ds_write_b128 (staging) and per-lane row ds_read_b128 (compute) sit at
//   the LDS BW floor. Triple-buffered, ONE barrier per chunk. Global loads
//   for chunk i+1 issue before compute of chunk i (latency hidden); their
//   ds_write lands after compute (T14 split). W via scalar pipe (uniform).
// ---------------------------------------------------------------------------
__global__ __launch_bounds__(512, 4) void router_lds(
        const float* __restrict__ X, const float* __restrict__ Wt,
        const float* __restrict__ B, float* __restrict__ out) {
    __shared__ float xs[3][64 * 64];           // 3 x 16KB swizzled tiles
    __shared__ float ls[64][65];               // logits [token][expert], pad

    const int tid  = threadIdx.x;
    const int lane = tid & 63;
    const int wv   = __builtin_amdgcn_readfirstlane(tid >> 6); // 0..7
    const int e0   = wv * 8;
    const int tokb = blockIdx.x * 64;

    // staging map: thread -> (row r, 16B-block cb) of the [64][64] tile
    const int r_st  = tid >> 3;                // 0..63
    const int cb_st = tid & 7;                 // 0..7 (also stages cb+8)
    const float* g0 = X + (size_t)(tokb + r_st) * DIM + 4 * cb_st;
    const int wr0 = r_st * 256 + ((16 * cb_st)       ^ (16 * (r_st & 7)));
    const int wr1 = r_st * 256 + ((16 * (cb_st + 8)) ^ (16 * (r_st & 7)));

    // compute-side read map: lane = token row
    const int rb  = lane * 256;
    const int rsw = 16 * (lane & 7);
    const float* wbase = Wt + e0;

    float acc[8];
#pragma unroll
    for (int e = 0; e < 8; e++) acc[e] = 0.0f;

    char* xsb = (char*)&xs[0][0];

    // prologue: stage chunk 0 into buffer 0
    {
        f32x4 s0 = *(const f32x4*)(g0);
        f32x4 s1 = *(const f32x4*)(g0 + 8 * 4);
        *(f32x4*)(xsb + wr0) = s0;
        *(f32x4*)(xsb + wr1) = s1;
    }
    __syncthreads();

    int cur_off = 0;
#pragma unroll 1
    for (int it = 0; it < 32; ++it) {
        const int kb = it * 64;
        const int kn = (it < 31) ? kb + 64 : kb;       // clamped prefetch
        f32x4 s0 = *(const f32x4*)(g0 + kn);
        f32x4 s1 = *(const f32x4*)(g0 + kn + 32);

        const char* cur = xsb + cur_off + rb;
#pragma unroll
        for (int cb = 0; cb < 16; ++cb) {
            f32x4 xv = *(const f32x4*)(cur + ((16 * cb) ^ rsw));
#pragma unroll
            for (int j = 0; j < 4; ++j) {
                const float xvj = xv[j];
                const float* wr = wbase + (size_t)(kb + 4 * cb + j) * NEXP;
#pragma unroll
                for (int e = 0; e < 8; e++)
                    acc[e] = fmaf(xvj, wr[e], acc[e]);  // strict in-order chain
            }
        }

        const int nxt_off = (cur_off == 32768) ? 0 : cur_off + 16384;
        char* nxt = xsb + nxt_off;
        *(f32x4*)(nxt + wr0) = s0;                      // vmcnt waits AFTER compute
        *(f32x4*)(nxt + wr1) = s1;
        cur_off = nxt_off;
        __syncthreads();                                // one barrier per chunk
    }

    // bias (separate fp32 add, matching einsum + b) -> LDS
#pragma unroll
    for (int e = 0; e < 8; e++) ls[lane][e0 + e] = acc[e] + B[e0 + e];

    __syncthreads();

    // -------- phase 2: wave 0, lane = token (identical to passing R3/R4) ---
    if (tid < 64) {
        const int t2 = tokb + lane;
        float l[64];
#pragma unroll
        for (int e = 0; e < 64; e++) l[e] = ls[lane][e];

        float m = l[0];
#pragma unroll
        for (int e = 1; e < 64; e++) m = fmaxf(m, l[e]);

        // top-2 on logits, ascending scan, strict > => lowest-index ties
        float v1 = -3.4e38f, v2 = -3.4e38f;
        int   i1 = 0,        i2 = 0;
#pragma unroll
        for (int e = 0; e < 64; e++) {
            float v = l[e];
            if (v > v1)      { v2 = v1; i2 = i1; v1 = v; i1 = e; }
            else if (v > v2) { v2 = v;  i2 = e; }
        }

        float den = 0.0f;
#pragma unroll
        for (int e = 0; e < 64; e++) { l[e] = __expf(l[e] - m); den += l[e]; }
        const float inv = 1.0f / den;

#pragma unroll
        for (int q = 0; q < 16; q++) {
            f32x4 v;
#pragma unroll
            for (int j = 0; j < 4; j++) v[j] = l[q * 4 + j] * inv;
            *(f32x4*)(out + (size_t)t2 * 64 + q * 4) = v;
        }
        out[OFF_IDX + (size_t)t2 * 2 + 0] = (float)i1;
        out[OFF_IDX + (size_t)t2 * 2 + 1] = (float)i2;
        out[OFF_TSC + (size_t)t2 * 2 + 0] = __expf(v1 - m) * inv;
        out[OFF_TSC + (size_t)t2 * 2 + 1] = __expf(v2 - m) * inv;
    }
}

extern "C" void kernel_launch(void* const* d_in, const int* in_sizes, int n_in,
                              void* d_out, int out_size, void* d_ws, size_t ws_size,
                              hipStream_t stream) {
    const float* X = (const float*)d_in[0];   // [4,8192,2048] f32
    const float* W = (const float*)d_in[1];   // [64,2048] f32
    const float* b = (const float*)d_in[2];   // [64] f32
    float* out = (float*)d_out;
    float* Wt  = (float*)d_ws;                // 512 KB needed

    wtrans<<<512, 256, 0, stream>>>(W, Wt);
    router_lds<<<NTOK / 64, 512, 0, stream>>>(X, Wt, b, out);
}